// Round 5
// baseline (827.631 us; speedup 1.0000x reference)
//
#include <hip/hip_runtime.h>
#include <hip/hip_cooperative_groups.h>
#include <hip/hip_bf16.h>

namespace cg = cooperative_groups;

// Problem constants
constexpr int BB = 32;     // batch
constexpr int NN = 4096;   // tokens
constexpr int CC = 128;    // feat channels
constexpr int DD = 64;     // slot dim
constexpr int KK = 8;      // slots (slot 0 = bg, 1..7 = fg)
constexpr int HH = 128;    // mlp hidden
constexpr float SCALE = 0.125f;   // D^-0.5
constexpr float EPS_A = 1e-8f;
constexpr float LN_EPS = 1e-5f;

constexpr int NTIL = 64;   // 64-token tiles per batch in attention
constexpr int NCU  = 256;  // MI355X CUs

typedef __bf16 bfx8 __attribute__((ext_vector_type(8)));
typedef float f32x4 __attribute__((ext_vector_type(4)));

__device__ inline float wave_sum(float x) {
#pragma unroll
    for (int off = 32; off > 0; off >>= 1) x += __shfl_xor(x, off, 64);
    return x;
}

__device__ inline float lane_bcast(float v, int src) {
    return __uint_as_float(__builtin_amdgcn_readlane(__float_as_uint(v), src));
}

__device__ inline float sigmoidf_(float x) { return 1.f / (1.f + __expf(-x)); }

__device__ inline unsigned short bf16rne(float x) {
    unsigned u = __float_as_uint(x);
    unsigned r = u + 0x7fffu + ((u >> 16) & 1u);
    return (unsigned short)(r >> 16);
}
__device__ inline float bf16tof(unsigned short h) {
    return __uint_as_float(((unsigned)h) << 16);
}

struct MegaArgs {
    const float *feat, *slot_in, *nf_g, *nf_b, *Wk, *Wv;
    const float *qln_g, *qln_b, *Wq, *qbg_g, *qbg_b, *Wqbg;
    const float *gru_wih, *gru_whh, *gru_bih, *gru_bhh;
    const float *gbg_wih, *gbg_whh, *gbg_bih, *gbg_bhh;
    const float *res_g, *res_b, *res_w1, *res_b1, *res_w2, *res_b2;
    const float *rbg_g, *rbg_b, *rbg_w1, *rbg_b1, *rbg_w2, *rbg_b2;
    unsigned short *fragW;     // ws
    float *wT, *kT, *v, *q, *slots, *Upart, *Spart;   // ws
    float *out_slots, *out_attn;
};

// ---------------------------------------------------------------------------
// Wave-level slot update (one wave per (b,slot); lane owns d). upd = U/S ->
// GRU -> residual MLP -> slots; then q = LN(slots)@Wq.  Cross-lane via
// readlane; GRU weights from wT[m][d][192] (coalesced).
// ---------------------------------------------------------------------------
__device__ __forceinline__ void slot_update_wave(
    const MegaArgs& A, int b, int i, int lane, bool init, bool last)
{
    const int fg = (i != 0);
    const size_t slot_off = ((size_t)b * KK + i) * DD + lane;
    const float h = init ? A.slot_in[slot_off] : A.slots[slot_off];
    float newh = h;

    if (!init) {
        float sp = A.Spart[((size_t)b * NTIL + lane) * KK + i];
        sp = wave_sum(sp);
        float us = 0.f;
#pragma unroll 8
        for (int p = 0; p < NTIL; p++)
            us += A.Upart[(((size_t)b * NTIL + p) * KK + i) * DD + lane];
        const float upd = us / sp;

        const float* wih = A.wT + (size_t)(fg ? 0 : 2) * (DD * 3 * DD);
        const float* whh = wih + DD * 3 * DD;
        const float* bih = fg ? A.gru_bih : A.gbg_bih;
        const float* bhh = fg ? A.gru_bhh : A.gbg_bhh;
        float gi0 = bih[lane], gi1 = bih[DD + lane], gi2 = bih[2 * DD + lane];
        float gh0 = bhh[lane], gh1 = bhh[DD + lane], gh2 = bhh[2 * DD + lane];
#pragma unroll 4
        for (int d = 0; d < DD; d++) {
            const float ud = lane_bcast(upd, d);
            const float hd = lane_bcast(h, d);
            gi0 += ud * wih[d * 192 + lane];
            gi1 += ud * wih[d * 192 + DD + lane];
            gi2 += ud * wih[d * 192 + 2 * DD + lane];
            gh0 += hd * whh[d * 192 + lane];
            gh1 += hd * whh[d * 192 + DD + lane];
            gh2 += hd * whh[d * 192 + 2 * DD + lane];
        }
        const float r = sigmoidf_(gi0 + gh0);
        const float z = sigmoidf_(gi1 + gh1);
        const float ng = tanhf(gi2 + r * gh2);
        const float tmp = (1.f - z) * ng + z * h;

        const float m = wave_sum(tmp) * (1.f / DD);
        const float dv = tmp - m;
        const float var = wave_sum(dv * dv) * (1.f / DD);
        const float lnx = dv * rsqrtf(var + LN_EPS) * (fg ? A.res_g : A.rbg_g)[lane] +
                          (fg ? A.res_b : A.rbg_b)[lane];
        const float* w1 = fg ? A.res_w1 : A.rbg_w1;
        const float* b1 = fg ? A.res_b1 : A.rbg_b1;
        float a0 = b1[lane], a1 = b1[DD + lane];
#pragma unroll 4
        for (int d = 0; d < DD; d++) {
            const float xd = lane_bcast(lnx, d);
            a0 += xd * w1[d * HH + lane];
            a1 += xd * w1[d * HH + DD + lane];
        }
        a0 = fmaxf(a0, 0.f); a1 = fmaxf(a1, 0.f);
        const float* w2 = fg ? A.res_w2 : A.rbg_w2;
        float o = (fg ? A.res_b2 : A.rbg_b2)[lane];
#pragma unroll 4
        for (int j = 0; j < DD; j++)
            o += lane_bcast(a0, j) * w2[j * DD + lane];
#pragma unroll 4
        for (int j = 0; j < DD; j++)
            o += lane_bcast(a1, j) * w2[(DD + j) * DD + lane];
        newh = tmp + o;
    }

    A.slots[slot_off] = newh;
    if (last) A.out_slots[slot_off] = newh;

    const float m2 = wave_sum(newh) * (1.f / DD);
    const float d2 = newh - m2;
    const float v2 = wave_sum(d2 * d2) * (1.f / DD);
    const float lq = d2 * rsqrtf(v2 + LN_EPS) * (fg ? A.qln_g : A.qbg_g)[lane] +
                     (fg ? A.qln_b : A.qbg_b)[lane];
    const float* W = fg ? A.Wq : A.Wqbg;
    float qv = 0.f;
#pragma unroll 4
    for (int e = 0; e < DD; e++)
        qv += lane_bcast(lq, e) * W[e * DD + lane];
    A.q[slot_off] = qv;
}

// ---------------------------------------------------------------------------
// Whole pipeline as ONE cooperative kernel, grid-size-agnostic (grid-stride
// in every phase).  Phases separated by threadfence + grid.sync().
// ---------------------------------------------------------------------------
__global__ __launch_bounds__(256, 2) void mega(MegaArgs A)
{
    cg::grid_group grid = cg::this_grid();
    __shared__ char ubuf[32768];   // K1: xh_hi|xh_lo bf16 / ks[64][65] f32

    const int tid = threadIdx.x, w = tid >> 6, lane = tid & 63;
    const int G = gridDim.x;

    // ---------------- P0: prep (fragW, wT, slots/q init) ----------------
    for (int o = blockIdx.x * 256 + tid; o < 16384; o += G * 256) {
        const int j = o & 7, l = (o >> 3) & 63, nf = (o >> 9) & 7, ks = o >> 12;
        const int c = ks * 32 + ((l >> 4) << 3) + j;
        const int n = nf * 16 + (l & 15);
        const float wv = (n < DD) ? A.Wk[c * DD + n] : A.Wv[c * DD + (n - DD)];
        A.fragW[o] = bf16rne(wv);
    }
    for (int o = blockIdx.x * 256 + tid; o < 4 * DD * 3 * DD; o += G * 256) {
        const int m = o / (DD * 3 * DD);
        const int rem = o % (DD * 3 * DD);
        const int d = rem / (3 * DD), j = rem % (3 * DD);
        const float* W = (m == 0) ? A.gru_wih : (m == 1) ? A.gru_whh
                       : (m == 2) ? A.gbg_wih : A.gbg_whh;
        A.wT[o] = W[j * DD + d];
    }
    for (int task = blockIdx.x * 4 + w; task < BB * KK; task += G * 4)
        slot_update_wave(A, task >> 3, task & 7, lane, true, false);
    __threadfence();
    grid.sync();

    // ---------------- P1: x = LN(feat); [k|v] = x @ W (bf16 MFMA, 2-term) ---
    for (int tile = blockIdx.x; tile < BB * NN / 64; tile += G) {
        __syncthreads();   // ubuf free from previous tile
        const size_t row0 = (size_t)tile * 64;

        const float2 g2 = *(const float2*)&A.nf_g[2 * lane];
        const float2 b2 = *(const float2*)&A.nf_b[2 * lane];
#pragma unroll 4
        for (int r0 = 0; r0 < 16; r0++) {
            const int r = w * 16 + r0;
            const float2 x2 = *(const float2*)&A.feat[(row0 + r) * CC + 2 * lane];
            const float m = wave_sum(x2.x + x2.y) * (1.f / 128.f);
            const float d0 = x2.x - m, d1 = x2.y - m;
            const float var = wave_sum(d0 * d0 + d1 * d1) * (1.f / 128.f);
            const float rs = rsqrtf(var + LN_EPS);
            const float y0 = d0 * rs * g2.x + b2.x;
            const float y1 = d1 * rs * g2.y + b2.y;
            const unsigned short h0 = bf16rne(y0), h1 = bf16rne(y1);
            const unsigned short l0 = bf16rne(y0 - bf16tof(h0));
            const unsigned short l1 = bf16rne(y1 - bf16tof(h1));
            const int off = r * 256 + ((4 * lane) ^ ((r & 7) << 4));
            *(unsigned*)(ubuf + off) = (unsigned)h0 | ((unsigned)h1 << 16);
            *(unsigned*)(ubuf + 16384 + off) = (unsigned)l0 | ((unsigned)l1 << 16);
        }
        __syncthreads();

        f32x4 acc[8];
#pragma unroll
        for (int nf = 0; nf < 8; nf++) acc[nf] = (f32x4){0.f, 0.f, 0.f, 0.f};
        const int arow = w * 16 + (lane & 15);
        const int hi16 = lane >> 4;
        const int asw = (arow & 7) << 4;
#pragma unroll
        for (int ks = 0; ks < 4; ks++) {
            const int abyte = arow * 256 + ((ks * 64 + hi16 * 16) ^ asw);
            const bfx8 ah = __builtin_bit_cast(bfx8, *(const uint4*)(ubuf + abyte));
            const bfx8 al = __builtin_bit_cast(bfx8, *(const uint4*)(ubuf + 16384 + abyte));
#pragma unroll
            for (int nf = 0; nf < 8; nf++) {
                const bfx8 bw = __builtin_bit_cast(
                    bfx8, *(const uint4*)(A.fragW + ((ks * 8 + nf) * 64 + lane) * 8));
                acc[nf] = __builtin_amdgcn_mfma_f32_16x16x32_bf16(ah, bw, acc[nf], 0, 0, 0);
                acc[nf] = __builtin_amdgcn_mfma_f32_16x16x32_bf16(al, bw, acc[nf], 0, 0, 0);
            }
        }
        __syncthreads();   // xh dead; reuse ubuf as ks[64][65]

        float* kslds = (float*)ubuf;
        const int trow = w * 16 + (lane >> 4) * 4;   // C-frag row=(lane>>4)*4+reg
#pragma unroll
        for (int nf = 0; nf < 4; nf++) {
            const int d = nf * 16 + (lane & 15);
#pragma unroll
            for (int reg = 0; reg < 4; reg++)
                kslds[d * 65 + trow + reg] = acc[nf][reg];
        }
        {
            const size_t vbase = (row0 + trow) * DD + (lane & 15);
#pragma unroll
            for (int nf = 4; nf < 8; nf++) {
#pragma unroll
                for (int reg = 0; reg < 4; reg++)
                    A.v[vbase + (size_t)reg * DD + (nf - 4) * 16] = acc[nf][reg];
            }
        }
        __syncthreads();

        const int b = (int)(row0 >> 12);
        const int n0 = (int)(row0 & 4095);
#pragma unroll
        for (int t = 0; t < 16; t++) {
            const int idx = t * 256 + tid;
            const int d = idx >> 6, nn = idx & 63;
            A.kT[((size_t)b * DD + d) * NN + n0 + nn] = kslds[d * 65 + nn];
        }
    }
    __threadfence();
    grid.sync();

    // ---------------- P2..: 3 x [attention partials | slot update] ----------
    for (int it = 0; it < 3; it++) {
        for (int task = blockIdx.x * 4 + w; task < BB * NTIL; task += G * 4) {
            const int b = task >> 6, tile = task & 63;
            const int n = (tile << 6) + lane;

            float qreg[KK];
#pragma unroll
            for (int i = 0; i < KK; i++)
                qreg[i] = A.q[((size_t)b * KK + i) * DD + lane];

            const float* kp = A.kT + (size_t)b * DD * NN + n;
            float kv[DD];
#pragma unroll
            for (int d = 0; d < DD; d++) kv[d] = kp[(size_t)d * NN];

            float dots[KK];
#pragma unroll
            for (int i = 0; i < KK; i++) dots[i] = 0.f;
#pragma unroll
            for (int d = 0; d < DD; d++) {
                const float k_ = kv[d];
#pragma unroll
                for (int i = 0; i < KK; i++)
                    dots[i] += k_ * lane_bcast(qreg[i], d);
            }
            float mx = -1e30f;
#pragma unroll
            for (int i = 0; i < KK; i++) { dots[i] *= SCALE; mx = fmaxf(mx, dots[i]); }
            float s = 0.f, e[KK];
#pragma unroll
            for (int i = 0; i < KK; i++) { e[i] = __expf(dots[i] - mx); s += e[i]; }
            const float inv = 1.f / s;
            float a[KK], sv[KK];
#pragma unroll
            for (int i = 0; i < KK; i++) { a[i] = e[i] * inv + EPS_A; sv[i] = a[i]; }

            if (it == 2) {
#pragma unroll
                for (int i = 0; i < KK; i++)
                    A.out_attn[((size_t)b * KK + i) * NN + n] = a[i];
            }
#pragma unroll
            for (int off = 32; off > 0; off >>= 1) {
#pragma unroll
                for (int i = 0; i < KK; i++) sv[i] += __shfl_xor(sv[i], off, 64);
            }
            if (lane == 0) {
#pragma unroll
                for (int i = 0; i < KK; i++)
                    A.Spart[(size_t)task * KK + i] = sv[i];
            }

            const float* vp = A.v + ((size_t)b * NN + (tile << 6)) * DD + lane;
            float vv[64];
#pragma unroll
            for (int t = 0; t < 64; t++) vv[t] = vp[t * DD];

            float U[KK];
#pragma unroll
            for (int i = 0; i < KK; i++) U[i] = 0.f;
#pragma unroll
            for (int t = 0; t < 64; t++) {
                const float vx = vv[t];
#pragma unroll
                for (int i = 0; i < KK; i++)
                    U[i] += lane_bcast(a[i], t) * vx;
            }
#pragma unroll
            for (int i = 0; i < KK; i++)
                A.Upart[((size_t)task * KK + i) * DD + lane] = U[i];
        }
        __threadfence();
        grid.sync();

        for (int task = blockIdx.x * 4 + w; task < BB * KK; task += G * 4)
            slot_update_wave(A, task >> 3, task & 7, lane, false, it == 2);
        __threadfence();
        grid.sync();
    }
}

// ===========================================================================
// Fallback multi-kernel path (round-3, verified passing) — used only if the
// cooperative launch is rejected by the runtime.
// ===========================================================================
__global__ __launch_bounds__(256) void k0_prepw(
    const float* __restrict__ Wk, const float* __restrict__ Wv,
    unsigned short* __restrict__ fragW)
{
    const int o = blockIdx.x * 256 + threadIdx.x;
    const int j = o & 7, l = (o >> 3) & 63, nf = (o >> 9) & 7, ks = o >> 12;
    const int c = ks * 32 + ((l >> 4) << 3) + j;
    const int n = nf * 16 + (l & 15);
    const float w = (n < DD) ? Wk[c * DD + n] : Wv[c * DD + (n - DD)];
    fragW[o] = bf16rne(w);
}

__global__ __launch_bounds__(256) void k0_prepg(
    const float* __restrict__ fg_ih, const float* __restrict__ fg_hh,
    const float* __restrict__ bg_ih, const float* __restrict__ bg_hh,
    float* __restrict__ wT)
{
    const int o = blockIdx.x * 256 + threadIdx.x;
    const int m = o / (DD * 3 * DD);
    const int rem = o % (DD * 3 * DD);
    const int d = rem / (3 * DD), j = rem % (3 * DD);
    const float* W = (m == 0) ? fg_ih : (m == 1) ? fg_hh : (m == 2) ? bg_ih : bg_hh;
    wT[o] = W[j * DD + d];
}

__global__ __launch_bounds__(256, 4) void k1_mfma(
    const float* __restrict__ feat, const float* __restrict__ nf_g,
    const float* __restrict__ nf_b, const unsigned short* __restrict__ fragW,
    float* __restrict__ kT, float* __restrict__ vout)
{
    __shared__ char ubuf[32768];
    const int tid = threadIdx.x, w = tid >> 6, lane = tid & 63;
    const size_t row0 = (size_t)blockIdx.x * 64;
    const float2 g2 = *(const float2*)&nf_g[2 * lane];
    const float2 b2 = *(const float2*)&nf_b[2 * lane];
#pragma unroll 4
    for (int r0 = 0; r0 < 16; r0++) {
        const int r = w * 16 + r0;
        const float2 x2 = *(const float2*)&feat[(row0 + r) * CC + 2 * lane];
        const float m = wave_sum(x2.x + x2.y) * (1.f / 128.f);
        const float d0 = x2.x - m, d1 = x2.y - m;
        const float var = wave_sum(d0 * d0 + d1 * d1) * (1.f / 128.f);
        const float rs = rsqrtf(var + LN_EPS);
        const float y0 = d0 * rs * g2.x + b2.x;
        const float y1 = d1 * rs * g2.y + b2.y;
        const unsigned short h0 = bf16rne(y0), h1 = bf16rne(y1);
        const unsigned short l0 = bf16rne(y0 - bf16tof(h0));
        const unsigned short l1 = bf16rne(y1 - bf16tof(h1));
        const int off = r * 256 + ((4 * lane) ^ ((r & 7) << 4));
        *(unsigned*)(ubuf + off) = (unsigned)h0 | ((unsigned)h1 << 16);
        *(unsigned*)(ubuf + 16384 + off) = (unsigned)l0 | ((unsigned)l1 << 16);
    }
    __syncthreads();
    f32x4 acc[8];
#pragma unroll
    for (int nf = 0; nf < 8; nf++) acc[nf] = (f32x4){0.f, 0.f, 0.f, 0.f};
    const int arow = w * 16 + (lane & 15);
    const int hi16 = lane >> 4;
    const int asw = (arow & 7) << 4;
#pragma unroll
    for (int ks = 0; ks < 4; ks++) {
        const int abyte = arow * 256 + ((ks * 64 + hi16 * 16) ^ asw);
        const bfx8 ah = __builtin_bit_cast(bfx8, *(const uint4*)(ubuf + abyte));
        const bfx8 al = __builtin_bit_cast(bfx8, *(const uint4*)(ubuf + 16384 + abyte));
#pragma unroll
        for (int nf = 0; nf < 8; nf++) {
            const bfx8 bw = __builtin_bit_cast(
                bfx8, *(const uint4*)(fragW + ((ks * 8 + nf) * 64 + lane) * 8));
            acc[nf] = __builtin_amdgcn_mfma_f32_16x16x32_bf16(ah, bw, acc[nf], 0, 0, 0);
            acc[nf] = __builtin_amdgcn_mfma_f32_16x16x32_bf16(al, bw, acc[nf], 0, 0, 0);
        }
    }
    __syncthreads();
    float* kslds = (float*)ubuf;
    const int trow = w * 16 + (lane >> 4) * 4;
#pragma unroll
    for (int nf = 0; nf < 4; nf++) {
        const int d = nf * 16 + (lane & 15);
#pragma unroll
        for (int reg = 0; reg < 4; reg++)
            kslds[d * 65 + trow + reg] = acc[nf][reg];
    }
    {
        const size_t vbase = (row0 + trow) * DD + (lane & 15);
#pragma unroll
        for (int nf = 4; nf < 8; nf++) {
#pragma unroll
            for (int reg = 0; reg < 4; reg++)
                vout[vbase + (size_t)reg * DD + (nf - 4) * 16] = acc[nf][reg];
        }
    }
    __syncthreads();
    const int b = (int)(row0 >> 12);
    const int n0 = (int)(row0 & 4095);
#pragma unroll
    for (int t = 0; t < 16; t++) {
        const int idx = t * 256 + tid;
        const int d = idx >> 6, nn = idx & 63;
        kT[((size_t)b * DD + d) * NN + n0 + nn] = kslds[d * 65 + nn];
    }
}

__global__ __launch_bounds__(64) void k2_attn(
    const float* __restrict__ kT, const float* __restrict__ v,
    const float* __restrict__ q, float* __restrict__ Upart,
    float* __restrict__ Spart, float* __restrict__ attn_out)
{
    const int blk = blockIdx.x;
    const int b = blk >> 6, tile = blk & 63;
    const int lane = threadIdx.x;
    const int n = (tile << 6) + lane;

    float qreg[KK];
#pragma unroll
    for (int i = 0; i < KK; i++) qreg[i] = q[((size_t)b * KK + i) * DD + lane];

    const float* kp = kT + (size_t)b * DD * NN + n;
    float kv[DD];
#pragma unroll
    for (int d = 0; d < DD; d++) kv[d] = kp[(size_t)d * NN];

    float dots[KK];
#pragma unroll
    for (int i = 0; i < KK; i++) dots[i] = 0.f;
#pragma unroll
    for (int d = 0; d < DD; d++) {
        const float k_ = kv[d];
#pragma unroll
        for (int i = 0; i < KK; i++)
            dots[i] += k_ * lane_bcast(qreg[i], d);
    }
    float m = -1e30f;
#pragma unroll
    for (int i = 0; i < KK; i++) { dots[i] *= SCALE; m = fmaxf(m, dots[i]); }
    float s = 0.f, e[KK];
#pragma unroll
    for (int i = 0; i < KK; i++) { e[i] = __expf(dots[i] - m); s += e[i]; }
    const float inv = 1.f / s;
    float a[KK], sv[KK];
#pragma unroll
    for (int i = 0; i < KK; i++) { a[i] = e[i] * inv + EPS_A; sv[i] = a[i]; }

    if (attn_out) {
#pragma unroll
        for (int i = 0; i < KK; i++)
            attn_out[((size_t)b * KK + i) * NN + n] = a[i];
    }
#pragma unroll
    for (int off = 32; off > 0; off >>= 1) {
#pragma unroll
        for (int i = 0; i < KK; i++) sv[i] += __shfl_xor(sv[i], off, 64);
    }
    if (lane == 0) {
#pragma unroll
        for (int i = 0; i < KK; i++) Spart[(size_t)blk * KK + i] = sv[i];
    }

    const float* vp = v + ((size_t)b * NN + (tile << 6)) * DD + lane;
    float vv[64];
#pragma unroll
    for (int t = 0; t < 64; t++) vv[t] = vp[t * DD];

    float U[KK];
#pragma unroll
    for (int i = 0; i < KK; i++) U[i] = 0.f;
#pragma unroll
    for (int t = 0; t < 64; t++) {
        const float vx = vv[t];
#pragma unroll
        for (int i = 0; i < KK; i++)
            U[i] += lane_bcast(a[i], t) * vx;
    }
#pragma unroll
    for (int i = 0; i < KK; i++)
        Upart[((size_t)blk * KK + i) * DD + lane] = U[i];
}

__global__ __launch_bounds__(64) void k3_update(MegaArgs A, int it)
{
    const int task = blockIdx.x;    // b*8 + i
    slot_update_wave(A, task >> 3, task & 7, (int)threadIdx.x,
                     it < 0, it == 2);
}

// ---------------------------------------------------------------------------
extern "C" void kernel_launch(void* const* d_in, const int* in_sizes, int n_in,
                              void* d_out, int out_size, void* d_ws, size_t ws_size,
                              hipStream_t stream)
{
    MegaArgs a;
    a.feat    = (const float*)d_in[0];
    a.slot_in = (const float*)d_in[1];
    a.nf_g    = (const float*)d_in[2];
    a.nf_b    = (const float*)d_in[3];
    a.Wk      = (const float*)d_in[4];
    a.Wv      = (const float*)d_in[5];
    a.qln_g   = (const float*)d_in[6];
    a.qln_b   = (const float*)d_in[7];
    a.Wq      = (const float*)d_in[8];
    a.qbg_g   = (const float*)d_in[9];
    a.qbg_b   = (const float*)d_in[10];
    a.Wqbg    = (const float*)d_in[11];
    a.gru_wih = (const float*)d_in[12];
    a.gru_whh = (const float*)d_in[13];
    a.gru_bih = (const float*)d_in[14];
    a.gru_bhh = (const float*)d_in[15];
    a.gbg_wih = (const float*)d_in[16];
    a.gbg_whh = (const float*)d_in[17];
    a.gbg_bih = (const float*)d_in[18];
    a.gbg_bhh = (const float*)d_in[19];
    a.res_g   = (const float*)d_in[20];
    a.res_b   = (const float*)d_in[21];
    a.res_w1  = (const float*)d_in[22];
    a.res_b1  = (const float*)d_in[23];
    a.res_w2  = (const float*)d_in[24];
    a.res_b2  = (const float*)d_in[25];
    a.rbg_g   = (const float*)d_in[26];
    a.rbg_b   = (const float*)d_in[27];
    a.rbg_w1  = (const float*)d_in[28];
    a.rbg_b1  = (const float*)d_in[29];
    a.rbg_w2  = (const float*)d_in[30];
    a.rbg_b2  = (const float*)d_in[31];

    char* ws = (char*)d_ws;
    size_t off = 0;
    a.fragW = (unsigned short*)(ws + off); off += 16384 * 2;
    off = (off + 255) & ~(size_t)255;
    a.wT    = (float*)(ws + off); off += 4 * DD * 3 * DD * 4;
    a.kT    = (float*)(ws + off); off += (size_t)BB * DD * NN * 4;
    a.v     = (float*)(ws + off); off += (size_t)BB * NN * DD * 4;
    a.q     = (float*)(ws + off); off += (size_t)BB * KK * DD * 4;
    a.slots = (float*)(ws + off); off += (size_t)BB * KK * DD * 4;
    a.Upart = (float*)(ws + off); off += (size_t)BB * NTIL * KK * DD * 4;
    a.Spart = (float*)(ws + off); off += (size_t)BB * NTIL * KK * 4;
    if (off > ws_size) return;

    a.out_slots = (float*)d_out;
    a.out_attn  = (float*)d_out + BB * KK * DD;

    // --- try the cooperative single-kernel path ---
    hipError_t lerr = hipErrorUnknown;
    int maxb = 0;
    if (hipOccupancyMaxActiveBlocksPerMultiprocessor(
            &maxb, reinterpret_cast<const void*>(mega), 256, 0) == hipSuccess &&
        maxb > 0) {
        int grid = maxb * NCU;
        if (grid > 512) grid = 512;
        void* kargs[] = { &a };
        lerr = hipLaunchCooperativeKernel(reinterpret_cast<void*>(mega),
                                          dim3(grid), dim3(256), kargs, 0, stream);
    }
    if (lerr == hipSuccess) return;
    (void)hipGetLastError();   // clear sticky error; fall back

    // --- fallback: verified multi-kernel pipeline (round-3) ---
    k0_prepw<<<64, 256, 0, stream>>>(a.Wk, a.Wv, a.fragW);
    k0_prepg<<<192, 256, 0, stream>>>(a.gru_wih, a.gru_whh, a.gbg_wih, a.gbg_whh, a.wT);
    k3_update<<<BB * KK, 64, 0, stream>>>(a, -1);
    k1_mfma<<<BB * NN / 64, 256, 0, stream>>>(a.feat, a.nf_g, a.nf_b, a.fragW, a.kT, a.v);
    for (int it = 0; it < 3; it++) {
        k2_attn<<<BB * NTIL, 64, 0, stream>>>(
            a.kT, a.v, a.q, a.Upart, a.Spart, it == 2 ? a.out_attn : nullptr);
        k3_update<<<BB * KK, 64, 0, stream>>>(a, it);
    }
}